// Round 8
// baseline (76.388 us; speedup 1.0000x reference)
//
#include <hip/hip_runtime.h>
#include <hip/hip_bf16.h>

// T=256, B=8, H1=512, U=64, H2=512, V=128
// out[b,t,u,v] = f[t,b,:]·W[:512,v] + g[b,u,:]·W[512:,v] + bias[v]; f_lens tail.
// K1: W -> Wt (128 x 1024 bf16, transposed).  K2 (512 blocks = b x 4t): per block
// compute pg panel (redundant per t-chunk, L2-hot Wt) + pf rows via barrier-free
// MFMA loop (B-frags = contiguous 16B loads from Wt), results in LDS, then stream
// 128 KB coalesced stores.
// R4/R5: no in-kernel cross-block sync. R7: no in-loop barriers / LDS B-staging
// at 1 block/CU — latency-serialized (MfmaUtil 2%, 45us).

typedef float  f32x4 __attribute__((ext_vector_type(4)));
typedef short  bh8   __attribute__((ext_vector_type(8)));

__device__ __forceinline__ unsigned short f2bf(float x) {
    unsigned u = __float_as_uint(x);
    return (unsigned short)((u + 0x7FFFu + ((u >> 16) & 1u)) >> 16);
}

__device__ __forceinline__ bh8 cvt8(f32x4 a, f32x4 b) {
    bh8 r;
    r[0] = (short)f2bf(a[0]); r[1] = (short)f2bf(a[1]);
    r[2] = (short)f2bf(a[2]); r[3] = (short)f2bf(a[3]);
    r[4] = (short)f2bf(b[0]); r[5] = (short)f2bf(b[1]);
    r[6] = (short)f2bf(b[2]); r[7] = (short)f2bf(b[3]);
    return r;
}

// ---------------- K1: W (1024x128 f32) -> Wt (128x1024 bf16) ------------------------
__global__ __launch_bounds__(256) void wtrans(const float* __restrict__ W,
                                              short* __restrict__ Wt) {
    int gid = blockIdx.x * 256 + threadIdx.x;    // 32 blocks
    int v = gid & 127, h0 = (gid >> 7) * 16;
    short tmp[16];
#pragma unroll
    for (int i = 0; i < 16; ++i) tmp[i] = (short)f2bf(W[(h0 + i) * 128 + v]);
    bh8* dst = reinterpret_cast<bh8*>(Wt + v * 1024 + h0);
    dst[0] = *reinterpret_cast<bh8*>(&tmp[0]);
    dst[1] = *reinterpret_cast<bh8*>(&tmp[8]);
}

// ---------------- K2: fused joint, 512 blocks = (b, 4 t-rows) -----------------------
__global__ __launch_bounds__(256) void joint2(const float* __restrict__ F,
                                              const float* __restrict__ G,
                                              const short* __restrict__ Wt,
                                              const float* __restrict__ bias,
                                              const int* __restrict__ f_lens,
                                              float* __restrict__ out,
                                              int lens_off) {
    __shared__ float pgs[64][132];       // ~33 KB, padded: 2-way max conflicts
    __shared__ float pfs[4][132];        //  ~2 KB

    const int tid = threadIdx.x;
    const int b  = blockIdx.x >> 6;
    const int t0 = (blockIdx.x & 63) * 4;
    const int w = tid >> 6, lane = tid & 63, l15 = lane & 15, cg = lane >> 4;

    // A row pointers: wave w owns pg u-tile [16w,16w+16); pf rows t0..t0+3 (dup x4)
    const float* grow = G + (b * 64 + w * 16 + l15) * 512;
    const float* frow = F + ((t0 + (l15 & 3)) * 8 + b) * 512;

    f32x4 accg[8] = {};
    f32x4 accf[2] = {};

    // barrier-free K-loop: 16 steps of 32
#pragma unroll 4
    for (int s = 0; s < 16; ++s) {
        const int k0 = s * 32 + cg * 8;
        f32x4 g0 = *reinterpret_cast<const f32x4*>(grow + k0);
        f32x4 g1 = *reinterpret_cast<const f32x4*>(grow + k0 + 4);
        bh8 ag = cvt8(g0, g1);
#pragma unroll
        for (int j = 0; j < 8; ++j) {    // pg: B = Wt[v][512+k], 16B contiguous
            bh8 bg = *reinterpret_cast<const bh8*>(Wt + (j * 16 + l15) * 1024 + 512 + k0);
            accg[j] = __builtin_amdgcn_mfma_f32_16x16x32_bf16(ag, bg, accg[j], 0, 0, 0);
        }
        f32x4 f0 = *reinterpret_cast<const f32x4*>(frow + k0);
        f32x4 f1 = *reinterpret_cast<const f32x4*>(frow + k0 + 4);
        bh8 af = cvt8(f0, f1);
#pragma unroll
        for (int jj = 0; jj < 2; ++jj) { // pf: wave w owns cols [32w, 32w+32)
            bh8 bf = *reinterpret_cast<const bh8*>(Wt + ((2 * w + jj) * 16 + l15) * 1024 + k0);
            accf[jj] = __builtin_amdgcn_mfma_f32_16x16x32_bf16(af, bf, accf[jj], 0, 0, 0);
        }
    }

    // results to LDS (D map: col = j*16+l15, row m = cg*4+q)
#pragma unroll
    for (int j = 0; j < 8; ++j)
#pragma unroll
        for (int q = 0; q < 4; ++q)
            pgs[w * 16 + cg * 4 + q][j * 16 + l15] = accg[j][q];
    if (cg == 0) {                       // pf rows m>=4 duplicate m&3
#pragma unroll
        for (int jj = 0; jj < 2; ++jj)
#pragma unroll
            for (int q = 0; q < 4; ++q)
                pfs[q][(2 * w + jj) * 16 + l15] = accf[jj][q];
    }
    __syncthreads();

    // store phase: 128 KB coalesced
    const int vq = tid & 31, ug = tid >> 5;
    const f32x4 bi = *reinterpret_cast<const f32x4*>(bias + vq * 4);
    f32x4 pfv[4];
#pragma unroll
    for (int t2 = 0; t2 < 4; ++t2)
        pfv[t2] = *reinterpret_cast<const f32x4*>(&pfs[t2][vq * 4]) + bi;

    float* ob = out + (size_t)(b * 256 + t0) * 8192;
#pragma unroll
    for (int ui = 0; ui < 8; ++ui) {
        const int u = ui * 8 + ug;
        f32x4 pgv = *reinterpret_cast<const f32x4*>(&pgs[u][vq * 4]);
#pragma unroll
        for (int t2 = 0; t2 < 4; ++t2)
            *reinterpret_cast<f32x4*>(ob + (t2 * 64 + u) * 128 + vq * 4) = pfv[t2] + pgv;
    }

    if (blockIdx.x == 0 && tid < 8) out[lens_off + tid] = (float)f_lens[tid];
}

extern "C" void kernel_launch(void* const* d_in, const int* in_sizes, int n_in,
                              void* d_out, int out_size, void* d_ws, size_t ws_size,
                              hipStream_t stream) {
    const float* f      = (const float*)d_in[0];
    const int*   f_lens = (const int*)  d_in[1];
    const float* g      = (const float*)d_in[2];
    // d_in[3] = g_lens (unused by reference output)
    const float* W      = (const float*)d_in[4];
    const float* bias   = (const float*)d_in[5];
    float* out = (float*)d_out;

    short* Wt = (short*)d_ws;                                  // 256 KB

    wtrans<<<dim3(32),  dim3(256), 0, stream>>>(W, Wt);
    joint2<<<dim3(512), dim3(256), 0, stream>>>(f, g, Wt, bias, f_lens, out, out_size - 8);
}

// Round 10
// 43.373 us; speedup vs baseline: 1.7612x; 1.7612x over previous
//
#include <hip/hip_runtime.h>
#include <hip/hip_bf16.h>

// T=256, B=8, H1=512, U=64, H2=512, V=128
// out[b,t,u,v] = f[t,b,:]·W[:512,v] + g[b,u,:]·W[512:,v] + bias[v]; f_lens tail (8).
// K1 pgk (64 blocks): pg GEMM — R6's proven proj3 path (bf16 MFMA, scalar W gathers
//   from raw f32 W), pg rows only -> Pg (256 KB ws).
// K2 fuse (512 blocks = b x 4t): pf in PURE F32 VALU (per-thread W-column dot,
//   coalesced W loads, wave-uniform f loads) + Pg panel prefetched to LDS +
//   R6's proven broadcast-store phase. One barrier total. 34 KB LDS -> 2 blocks/CU.
// Journal: R4/R5 no in-kernel cross-block sync (agent fences nuke write BW).
//   R7: no per-step barriers at 1 blk/CU. R8/R9: ws-produced bf16 fragment tables
//   consumed directly by MFMA gave unexplained absmax anomalies (3.15 / 126) despite
//   verified addressing — path abandoned; pf needs no W preprocessing at all.

typedef float  f32x4 __attribute__((ext_vector_type(4)));
typedef short  bh8   __attribute__((ext_vector_type(8)));

__device__ __forceinline__ unsigned short f2bf(float x) {
    unsigned u = __float_as_uint(x);
    return (unsigned short)((u + 0x7FFFu + ((u >> 16) & 1u)) >> 16);
}

__device__ __forceinline__ bh8 cvt8(f32x4 a, f32x4 b) {
    bh8 r;
    r[0] = (short)f2bf(a[0]); r[1] = (short)f2bf(a[1]);
    r[2] = (short)f2bf(a[2]); r[3] = (short)f2bf(a[3]);
    r[4] = (short)f2bf(b[0]); r[5] = (short)f2bf(b[1]);
    r[6] = (short)f2bf(b[2]); r[7] = (short)f2bf(b[3]);
    return r;
}

// ---------------- K1: pg GEMM (R6 proj3, pg rows only), 64 blocks x 8 rows ----------
__global__ __launch_bounds__(256) void pgk(const float* __restrict__ G,
                                           const float* __restrict__ W,
                                           float* __restrict__ Pg) {
    __shared__ float sred[4][8][128];            // 16 KB
    const int tid = threadIdx.x;
    const int rows8 = blockIdx.x * 8;            // 0..504
    const int w = tid >> 6, lane = tid & 63, l15 = lane & 15, cc = lane >> 4;
    const float* arow = G + (rows8 + (l15 & 7)) * 512;

    f32x4 acc[8] = {};
#pragma unroll
    for (int kk = 0; kk < 4; ++kk) {
        const int k0 = w * 128 + kk * 32 + cc * 8;
        f32x4 a0 = *reinterpret_cast<const f32x4*>(arow + k0);
        f32x4 a1 = *reinterpret_cast<const f32x4*>(arow + k0 + 4);
        bh8 av = cvt8(a0, a1);
#pragma unroll
        for (int j = 0; j < 8; ++j) {
            const float* wsrc = W + (512 + k0) * 128 + (j * 16 + l15);
            bh8 bv;
#pragma unroll
            for (int i = 0; i < 8; ++i) bv[i] = (short)f2bf(wsrc[i * 128]);
            acc[j] = __builtin_amdgcn_mfma_f32_16x16x32_bf16(av, bv, acc[j], 0, 0, 0);
        }
    }
    if (cc < 2) {                                // D rows m = cc*4+q in [0,8); m>=8 dup
#pragma unroll
        for (int j = 0; j < 8; ++j)
#pragma unroll
            for (int q = 0; q < 4; ++q)
                sred[w][cc * 4 + q][j * 16 + l15] = acc[j][q];
    }
    __syncthreads();

    const int row = tid >> 5, colq = tid & 31;
    f32x4 s = *reinterpret_cast<const f32x4*>(&sred[0][row][colq * 4]);
    s += *reinterpret_cast<const f32x4*>(&sred[1][row][colq * 4]);
    s += *reinterpret_cast<const f32x4*>(&sred[2][row][colq * 4]);
    s += *reinterpret_cast<const f32x4*>(&sred[3][row][colq * 4]);
    *reinterpret_cast<f32x4*>(Pg + (rows8 + row) * 128 + colq * 4) = s;
}

// ---------------- K2: fused pf (f32 VALU) + broadcast store, 512 blocks -------------
__global__ __launch_bounds__(256) void fuse(const float* __restrict__ F,
                                            const float* __restrict__ W,
                                            const float* __restrict__ Pg,
                                            const float* __restrict__ bias,
                                            const int* __restrict__ f_lens,
                                            float* __restrict__ out,
                                            int lens_off) {
    __shared__ float pgs[64 * 128];      // 32 KB
    __shared__ float pfs[4][128];        //  2 KB

    const int tid = threadIdx.x;
    const int b  = blockIdx.x >> 6;
    const int t0 = (blockIdx.x & 63) * 4;

    // ---- issue Pg panel prefetch (latency hides under pf loop) ----
    const f32x4* pgsrc = reinterpret_cast<const f32x4*>(Pg + b * 8192);
    f32x4 pgin[8];
#pragma unroll
    for (int i = 0; i < 8; ++i) pgin[i] = pgsrc[i * 256 + tid];

    // ---- pf in pure f32: thread = (v = tid&127, rr = tid>>7 -> t-rows 2rr, 2rr+1) ---
    const int v = tid & 127, rr = tid >> 7;
    const float* f0 = F + ((t0 + 2 * rr) * 8 + b) * 512;       // f is [T][B][H1]
    const float* f1 = F + ((t0 + 2 * rr + 1) * 8 + b) * 512;

    f32x4 a0 = {}, a1 = {};
#pragma unroll 4
    for (int k = 0; k < 512; k += 4) {
        f32x4 wv;
        wv[0] = W[(k + 0) * 128 + v];    // coalesced: lanes read consecutive v
        wv[1] = W[(k + 1) * 128 + v];
        wv[2] = W[(k + 2) * 128 + v];
        wv[3] = W[(k + 3) * 128 + v];
        f32x4 fv0 = *reinterpret_cast<const f32x4*>(f0 + k);   // wave-uniform
        f32x4 fv1 = *reinterpret_cast<const f32x4*>(f1 + k);
        a0 += fv0 * wv;
        a1 += fv1 * wv;
    }
    pfs[2 * rr + 0][v] = a0[0] + a0[1] + a0[2] + a0[3];
    pfs[2 * rr + 1][v] = a1[0] + a1[1] + a1[2] + a1[3];

    // ---- park Pg panel in LDS ----
#pragma unroll
    for (int i = 0; i < 8; ++i)
        *reinterpret_cast<f32x4*>(&pgs[(i * 256 + tid) * 4]) = pgin[i];

    __syncthreads();

    // ---- store phase: 64 KB coalesced (R6 bcast pattern, P from LDS) ----
    const int vq = tid & 31, ug = tid >> 5;
    const f32x4 bi = *reinterpret_cast<const f32x4*>(bias + vq * 4);
    f32x4 pfv[4];
#pragma unroll
    for (int t2 = 0; t2 < 4; ++t2)
        pfv[t2] = *reinterpret_cast<const f32x4*>(&pfs[t2][vq * 4]) + bi;

    float* ob = out + (size_t)(b * 256 + t0) * 8192;
#pragma unroll
    for (int ui = 0; ui < 8; ++ui) {
        const int u = ui * 8 + ug;
        f32x4 pgv = *reinterpret_cast<const f32x4*>(&pgs[u * 128 + vq * 4]);
#pragma unroll
        for (int t2 = 0; t2 < 4; ++t2)
            *reinterpret_cast<f32x4*>(ob + (t2 * 64 + u) * 128 + vq * 4) = pfv[t2] + pgv;
    }

    if (blockIdx.x == 0 && tid < 8) out[lens_off + tid] = (float)f_lens[tid];
}

extern "C" void kernel_launch(void* const* d_in, const int* in_sizes, int n_in,
                              void* d_out, int out_size, void* d_ws, size_t ws_size,
                              hipStream_t stream) {
    const float* f      = (const float*)d_in[0];
    const int*   f_lens = (const int*)  d_in[1];
    const float* g      = (const float*)d_in[2];
    // d_in[3] = g_lens (unused by reference output)
    const float* W      = (const float*)d_in[4];
    const float* bias   = (const float*)d_in[5];
    float* out = (float*)d_out;

    float* Pg = (float*)d_ws;                                  // 512*128*4 = 256 KB

    pgk <<<dim3(64),  dim3(256), 0, stream>>>(g, W, Pg);
    fuse<<<dim3(512), dim3(256), 0, stream>>>(f, W, Pg, bias, f_lens, out, out_size - 8);
}

// Round 11
// 26.671 us; speedup vs baseline: 2.8641x; 1.6262x over previous
//
#include <hip/hip_runtime.h>
#include <hip/hip_bf16.h>

// T=256, B=8, H1=512, U=64, H2=512, V=128
// out[b,t,u,v] = f[t,b,:]·W[:512,v] + g[b,u,:]·W[512:,v] + bias[v]; f_lens tail (8).
// K1 proj3 (320 blocks): ALL of P (pf+pg) via bf16 MFMA, B gathered from raw f32 W
//   (R6-proven: absmax 0.031, ~6us). K2 bcast4 (1024 blocks = b x 2t): pg panel ->
//   LDS (R10-proven prefetch), pf rows from P, 64 KB coalesced stores (R10-proven
//   store phase).
// Journal: R4/R5 no in-kernel cross-block sync (agent fences nuke write BW).
//   R7 no per-step barriers at 1 blk/CU. R8/R9 ws-bf16-fragment-table -> MFMA path
//   has unexplained absmax anomalies — abandoned. R10: VALU pf at 2 blk/CU is
//   load-latency bound (~25us) — pf must ride MFMA in a parallel dispatch.

typedef float  f32x4 __attribute__((ext_vector_type(4)));
typedef short  bh8   __attribute__((ext_vector_type(8)));

__device__ __forceinline__ unsigned short f2bf(float x) {
    unsigned u = __float_as_uint(x);
    return (unsigned short)((u + 0x7FFFu + ((u >> 16) & 1u)) >> 16);
}

__device__ __forceinline__ bh8 cvt8(f32x4 a, f32x4 b) {
    bh8 r;
    r[0] = (short)f2bf(a[0]); r[1] = (short)f2bf(a[1]);
    r[2] = (short)f2bf(a[2]); r[3] = (short)f2bf(a[3]);
    r[4] = (short)f2bf(b[0]); r[5] = (short)f2bf(b[1]);
    r[6] = (short)f2bf(b[2]); r[7] = (short)f2bf(b[3]);
    return r;
}

// ---------------- K1: P GEMM, 320 blocks x 8 rows, wave-split-K (4x128) -------------
// P rows 0..2047: pf (r = b*256+t);  rows 2048..2559: pg (r = 2048+b*64+u).
__global__ __launch_bounds__(256) void proj3(const float* __restrict__ F,
                                             const float* __restrict__ G,
                                             const float* __restrict__ W,
                                             float* __restrict__ P) {
    __shared__ float sred[4][8][128];            // 16 KB

    const int tid = threadIdx.x;
    const int rows8 = blockIdx.x * 8;            // P row base
    const bool isF = rows8 < 2048;
    const int koff = isF ? 0 : 512;
    const int w = tid >> 6, lane = tid & 63, l15 = lane & 15, cc = lane >> 4;

    const int rr = rows8 + (l15 & 7);
    const float* arow = isF ? F + (((rr & 255) << 3) + (rr >> 8)) * 512   // f[t][b][:]
                            : G + (rr - 2048) * 512;                      // g[b*64+u][:]

    f32x4 acc[8] = {};
#pragma unroll
    for (int kk = 0; kk < 4; ++kk) {
        const int k0 = w * 128 + kk * 32 + cc * 8;
        f32x4 a0 = *reinterpret_cast<const f32x4*>(arow + k0);
        f32x4 a1 = *reinterpret_cast<const f32x4*>(arow + k0 + 4);
        bh8 av = cvt8(a0, a1);
#pragma unroll
        for (int j = 0; j < 8; ++j) {
            const float* wsrc = W + (koff + k0) * 128 + (j * 16 + l15);
            bh8 bv;
#pragma unroll
            for (int i = 0; i < 8; ++i) bv[i] = (short)f2bf(wsrc[i * 128]);
            acc[j] = __builtin_amdgcn_mfma_f32_16x16x32_bf16(av, bv, acc[j], 0, 0, 0);
        }
    }
    if (cc < 2) {                                // D rows m = cc*4+q in [0,8); m>=8 dup
#pragma unroll
        for (int j = 0; j < 8; ++j)
#pragma unroll
            for (int q = 0; q < 4; ++q)
                sred[w][cc * 4 + q][j * 16 + l15] = acc[j][q];
    }
    __syncthreads();

    const int row = tid >> 5, colq = tid & 31;
    f32x4 s = *reinterpret_cast<const f32x4*>(&sred[0][row][colq * 4]);
    s += *reinterpret_cast<const f32x4*>(&sred[1][row][colq * 4]);
    s += *reinterpret_cast<const f32x4*>(&sred[2][row][colq * 4]);
    s += *reinterpret_cast<const f32x4*>(&sred[3][row][colq * 4]);
    *reinterpret_cast<f32x4*>(P + (rows8 + row) * 128 + colq * 4) = s;
}

// ---------------- K2: broadcast add, 1024 blocks = (b, 2 t-rows), panel in LDS ------
__global__ __launch_bounds__(256) void bcast4(const float* __restrict__ P,
                                              const float* __restrict__ bias,
                                              const int* __restrict__ f_lens,
                                              float* __restrict__ out,
                                              int lens_off) {
    __shared__ float pgs[64 * 128];      // 32 KB

    const int tid = threadIdx.x;
    const int b  = blockIdx.x >> 7;
    const int t0 = (blockIdx.x & 127) * 2;

    // prefetch pg panel (b) into regs (latency overlaps pf/bias reads)
    const f32x4* pgsrc = reinterpret_cast<const f32x4*>(P + (2048 + b * 64) * 128);
    f32x4 pgin[8];
#pragma unroll
    for (int i = 0; i < 8; ++i) pgin[i] = pgsrc[i * 256 + tid];

    // pf rows t0, t0+1 + bias
    const int vq = tid & 31, ug = tid >> 5;
    const f32x4 bi = *reinterpret_cast<const f32x4*>(bias + vq * 4);
    f32x4 pfv[2];
#pragma unroll
    for (int t2 = 0; t2 < 2; ++t2)
        pfv[t2] = *reinterpret_cast<const f32x4*>(P + (b * 256 + t0 + t2) * 128 + vq * 4) + bi;

    // park panel in LDS
#pragma unroll
    for (int i = 0; i < 8; ++i)
        *reinterpret_cast<f32x4*>(&pgs[(i * 256 + tid) * 4]) = pgin[i];
    __syncthreads();

    // store phase: 64 KB coalesced
    float* ob = out + (size_t)(b * 256 + t0) * 8192;
#pragma unroll
    for (int ui = 0; ui < 8; ++ui) {
        const int u = ui * 8 + ug;
        f32x4 pgv = *reinterpret_cast<const f32x4*>(&pgs[u * 128 + vq * 4]);
#pragma unroll
        for (int t2 = 0; t2 < 2; ++t2)
            *reinterpret_cast<f32x4*>(ob + (t2 * 64 + u) * 128 + vq * 4) = pfv[t2] + pgv;
    }

    if (blockIdx.x == 0 && tid < 8) out[lens_off + tid] = (float)f_lens[tid];
}

extern "C" void kernel_launch(void* const* d_in, const int* in_sizes, int n_in,
                              void* d_out, int out_size, void* d_ws, size_t ws_size,
                              hipStream_t stream) {
    const float* f      = (const float*)d_in[0];
    const int*   f_lens = (const int*)  d_in[1];
    const float* g      = (const float*)d_in[2];
    // d_in[3] = g_lens (unused by reference output)
    const float* W      = (const float*)d_in[4];
    const float* bias   = (const float*)d_in[5];
    float* out = (float*)d_out;

    float* P = (float*)d_ws;                                   // 2560*128*4 = 1.25 MB

    proj3 <<<dim3(320),  dim3(256), 0, stream>>>(f, g, W, P);
    bcast4<<<dim3(1024), dim3(256), 0, stream>>>(P, bias, f_lens, out, out_size - 8);
}